// Round 11
// baseline (195.940 us; speedup 1.0000x reference)
//
#include <hip/hip_runtime.h>
#include <hip/hip_bf16.h>

// Net_27358941675610: the 50-step scan collapses to its fixed point:
//   R   = 0.35*sigmoid((6/7)*(psp^T @ W_h^T + b_h))            [4096,2048]
//   out = 0.35*sigmoid(0.75*(R @ W_o^T + b_o) + 0.125*label)   [4096,512]
// Inputs fp32, output fp32. Internal: bf16 MFMA, fp32 acc.
// R11: GEMMs were LDS-BW-bound (72KB LDS traffic vs 258 cyc MFMA per
// block-iter). B-fragments now load DIRECTLY global->VGPR (16B/lane, 64B
// per 16-row group, L2-resident weights) -- B never touches LDS. A keeps
// the proven 8-row-chunk GLD staging + seg^(row&7) swizzle. 3 launches.

typedef __bf16 bf16_t;
typedef __bf16 bf16x8 __attribute__((ext_vector_type(8)));
typedef __bf16 bf16x4v __attribute__((ext_vector_type(4)));
typedef float f32x4 __attribute__((ext_vector_type(4)));

#define GLD_TO_LDS16(gp, lp)                                            \
  __builtin_amdgcn_global_load_lds(                                     \
      (__attribute__((address_space(1))) void*)(void*)(gp),             \
      (__attribute__((address_space(3))) void*)(lp), 16, 0, 0)

// ---- prep: psp transpose+cvt AND both weight cvts, one kernel ------------
// grid 1024 x 256. Block b: one 64x64 transpose tile + 768 float4 converts.
__global__ __launch_bounds__(256) void prep(
    const float* __restrict__ psp, bf16_t* __restrict__ pspT,
    const float4* __restrict__ w1, bf16x4v* __restrict__ o1, int n1,
    const float4* __restrict__ w2, bf16x4v* __restrict__ o2, int n2) {
  __shared__ float tile[64][65];
  const int tid = threadIdx.x;
  const int b = blockIdx.x;
  // transpose tile: psp [1024,4096] -> pspT [4096,1024]
  const int c0 = (b & 63) * 64;   // batch dim
  const int r0 = (b >> 6) * 64;   // in dim
  const int tx = tid & 63;
  const int ty = tid >> 6;
#pragma unroll
  for (int i = 0; i < 16; ++i) {
    const int r = ty + i * 4;
    tile[r][tx] = psp[(size_t)(r0 + r) * 4096 + c0 + tx];
  }
  // weight converts (independent of the LDS tile; do before barrier)
  const int base = b * 768 + tid;
#pragma unroll
  for (int i = 0; i < 3; ++i) {
    const int idx = base + i * 256;
    const float4 v = (idx < n1) ? w1[idx] : w2[idx - n1];
    bf16x4v o;
    o.x = (bf16_t)v.x; o.y = (bf16_t)v.y; o.z = (bf16_t)v.z; o.w = (bf16_t)v.w;
    if (idx < n1) o1[idx] = o;
    else if (idx - n1 < n2) o2[idx - n1] = o;
  }
  __syncthreads();
#pragma unroll
  for (int i = 0; i < 16; ++i) {
    const int r = ty + i * 4;
    pspT[(size_t)(c0 + r) * 1024 + r0 + tx] = (bf16_t)tile[tx][r];
  }
}

// ---- GEMM1: R(bf16) = 0.35*sigmoid(6/7*(A @ Bt^T + bias)) ----------------
// 128x64 tile, 4 waves of 64x32, BK=64, grid (32,32)=1024 -> 4 blk/CU.
// A: LDS-staged (8-row chunks, seg^(row&7) swizzle). B: direct global->VGPR.
__global__ __launch_bounds__(256, 4) void gemm1_nt(
    const bf16_t* __restrict__ A, const bf16_t* __restrict__ Bt,
    const float* __restrict__ bias, bf16_t* __restrict__ C,
    int M, int N, int K) {
  constexpr int BK = 64;
  __shared__ __align__(16) bf16_t sA[128 * BK];  // 16 KB

  const int tid = threadIdx.x;
  const int wave = tid >> 6;  // 0..3
  const int lane = tid & 63;
  const int bm = blockIdx.x * 128;
  const int bn = blockIdx.y * 64;
  const int wm = (wave & 1) * 64;
  const int wn = (wave >> 1) * 32;

  f32x4 acc[4][2] = {};

  const int srow8 = lane >> 3;
  const int gseg = (lane & 7) ^ srow8;
  const bf16_t* Ag = A + (size_t)(bm + wave * 32 + srow8) * K + gseg * 8;
  const int dstA = wave * 2048;

  const int fr = lane & 15;
  const int qh = lane >> 4;  // 0..3
  // B direct: lane reads Bt[bn+wn+j*16+fr][k0 + ks*32 + qh*8 ..+7] (16B)
  const bf16_t* Bj0 = Bt + (size_t)(bn + wn + fr) * K + qh * 8;
  const bf16_t* Bj1 = Bj0 + (size_t)16 * K;

  for (int k0 = 0; k0 < K; k0 += BK) {
#pragma unroll
    for (int c = 0; c < 4; ++c)
      GLD_TO_LDS16(Ag + (size_t)(c * 8) * K + k0, sA + dstA + c * 512);
    // issue B loads for both ks steps; latency hidden by the barrier drain
    bf16x8 bv[2][2];
    bv[0][0] = *(const bf16x8*)(Bj0 + k0);
    bv[0][1] = *(const bf16x8*)(Bj1 + k0);
    bv[1][0] = *(const bf16x8*)(Bj0 + k0 + 32);
    bv[1][1] = *(const bf16x8*)(Bj1 + k0 + 32);
    __syncthreads();  // drains vmcnt: A tiles published, B regs ready

#pragma unroll
    for (int ks = 0; ks < 2; ++ks) {
      const int q = ks * 4 + qh;
      bf16x8 av[4];
#pragma unroll
      for (int i = 0; i < 4; ++i) {
        const int rr = wm + i * 16 + fr;
        av[i] = *(const bf16x8*)(sA + rr * BK + ((q ^ (rr & 7)) * 8));
      }
#pragma unroll
      for (int i = 0; i < 4; ++i)
#pragma unroll
        for (int j = 0; j < 2; ++j)
          acc[i][j] = __builtin_amdgcn_mfma_f32_16x16x32_bf16(
              av[i], bv[ks][j], acc[i][j], 0, 0, 0);
    }
    __syncthreads();  // protects sA reuse
  }

  // epilogue: C/D layout col = lane&15, row = (lane>>4)*4 + r  (m89)
  const int cm0 = (lane >> 4) * 4;
#pragma unroll
  for (int j = 0; j < 2; ++j) {
    const int gn = bn + wn + j * 16 + fr;
    const float bj = bias[gn];
#pragma unroll
    for (int i = 0; i < 4; ++i) {
#pragma unroll
      for (int r = 0; r < 4; ++r) {
        const int gm = bm + wm + i * 16 + cm0 + r;
        const float z = 0.8571428571428571f * (acc[i][j][r] + bj);
        C[(size_t)gm * N + gn] = (bf16_t)(0.35f / (1.0f + __expf(-z)));
      }
    }
  }
}

// ---- GEMM2: out(fp32) = 0.35*sigmoid(0.75*(R @ Wo^T + b_o) + 0.125*lbl) --
// 32x64 tile, 4 waves of 16x32, BK=64, grid (128,8)=1024. B direct->VGPR.
__global__ __launch_bounds__(256, 4) void gemm2_nt(
    const bf16_t* __restrict__ A, const bf16_t* __restrict__ Bt,
    const float* __restrict__ bias, const float* __restrict__ lbl,
    float* __restrict__ out, int M, int N, int K) {
  constexpr int BK = 64;
  __shared__ __align__(16) bf16_t sA[32 * BK];  // 4 KB

  const int tid = threadIdx.x;
  const int wave = tid >> 6;
  const int lane = tid & 63;
  const int bm = blockIdx.x * 32;
  const int bn = blockIdx.y * 64;
  const int wm = (wave & 1) * 16;
  const int wn = (wave >> 1) * 32;

  f32x4 acc[2] = {};

  const int srow8 = lane >> 3;
  const int gseg = (lane & 7) ^ srow8;
  const bf16_t* Ag = A + (size_t)(bm + wave * 8 + srow8) * K + gseg * 8;
  const int dstA = wave * 512;

  const int fr = lane & 15;
  const int qh = lane >> 4;
  const bf16_t* Bj0 = Bt + (size_t)(bn + wn + fr) * K + qh * 8;
  const bf16_t* Bj1 = Bj0 + (size_t)16 * K;

  for (int k0 = 0; k0 < K; k0 += BK) {
    GLD_TO_LDS16(Ag + k0, sA + dstA);
    bf16x8 bv[2][2];
    bv[0][0] = *(const bf16x8*)(Bj0 + k0);
    bv[0][1] = *(const bf16x8*)(Bj1 + k0);
    bv[1][0] = *(const bf16x8*)(Bj0 + k0 + 32);
    bv[1][1] = *(const bf16x8*)(Bj1 + k0 + 32);
    __syncthreads();

#pragma unroll
    for (int ks = 0; ks < 2; ++ks) {
      const int q = ks * 4 + qh;
      const int ra = wm + fr;
      const bf16x8 av = *(const bf16x8*)(sA + ra * BK + ((q ^ (ra & 7)) * 8));
#pragma unroll
      for (int j = 0; j < 2; ++j)
        acc[j] = __builtin_amdgcn_mfma_f32_16x16x32_bf16(av, bv[ks][j],
                                                         acc[j], 0, 0, 0);
    }
    __syncthreads();
  }

  const int cm0 = (lane >> 4) * 4;
#pragma unroll
  for (int j = 0; j < 2; ++j) {
    const int gn = bn + wn + j * 16 + fr;
    const float bj = bias[gn];
#pragma unroll
    for (int r = 0; r < 4; ++r) {
      const int gm = bm + wm + cm0 + r;
      const float z =
          0.75f * (acc[j][r] + bj) + 0.125f * lbl[(size_t)gm * N + gn];
      out[(size_t)gm * N + gn] = 0.35f / (1.0f + __expf(-z));
    }
  }
}

extern "C" void kernel_launch(void* const* d_in, const int* in_sizes, int n_in,
                              void* d_out, int out_size, void* d_ws, size_t ws_size,
                              hipStream_t stream) {
  constexpr int IN = 1024, HID = 2048, OUT = 512, B = 4096;
  const float* psp = (const float*)d_in[0];   // [IN, B]
  const float* lbl = (const float*)d_in[1];   // [B, OUT]
  const float* W_h = (const float*)d_in[2];   // [HID, IN]
  const float* b_h = (const float*)d_in[3];   // [HID]
  const float* W_o = (const float*)d_in[4];   // [OUT, HID]
  const float* b_o = (const float*)d_in[5];   // [OUT]
  float* out = (float*)d_out;                 // [B, OUT] fp32

  bf16_t* Whb = (bf16_t*)d_ws;                 // [HID, IN]  4 MB
  bf16_t* Wob = Whb + (size_t)HID * IN;        // [OUT, HID] 2 MB
  bf16_t* pspT = Wob + (size_t)OUT * HID;      // [B, IN]    8 MB
  bf16_t* Rm = pspT + (size_t)B * IN;          // [B, HID]  16 MB

  prep<<<1024, 256, 0, stream>>>(
      psp, pspT, (const float4*)W_h, (bf16x4v*)Whb, HID * IN / 4,
      (const float4*)W_o, (bf16x4v*)Wob, OUT * HID / 4);
  gemm1_nt<<<dim3(B / 128, HID / 64), 256, 0, stream>>>(
      pspT, Whb, b_h, Rm, B, HID, IN);
  gemm2_nt<<<dim3(B / 32, OUT / 64), 256, 0, stream>>>(
      Rm, Wob, b_o, lbl, out, B, OUT, HID);
}

// Round 12
// 141.386 us; speedup vs baseline: 1.3859x; 1.3859x over previous
//
#include <hip/hip_runtime.h>
#include <hip/hip_bf16.h>

// Net_27358941675610: the 50-step scan collapses to its fixed point:
//   R   = 0.35*sigmoid((6/7)*(psp^T @ W_h^T + b_h))            [4096,2048]
//   out = 0.35*sigmoid(0.75*(R @ W_o^T + b_o) + 0.125*label)   [4096,512]
// Inputs fp32, output fp32. Internal: bf16 MFMA, fp32 acc.
// R12: R10 GEMM bodies (R11 B-direct gather reverted: 21.7GB over-fetch) +
// DETERMINISTIC double-buffer: forced `s_waitcnt vmcnt(0)` before every
// __syncthreads makes cross-wave GLD publication safe (R7's flake was the
// compiler NOT draining vmcnt at the barrier when prefetch hit the other buf).

typedef __bf16 bf16_t;
typedef __bf16 bf16x8 __attribute__((ext_vector_type(8)));
typedef __bf16 bf16x4v __attribute__((ext_vector_type(4)));
typedef float f32x4 __attribute__((ext_vector_type(4)));

#define GLD_TO_LDS16(gp, lp)                                            \
  __builtin_amdgcn_global_load_lds(                                     \
      (__attribute__((address_space(1))) void*)(void*)(gp),             \
      (__attribute__((address_space(3))) void*)(lp), 16, 0, 0)

#define DRAIN_VM() asm volatile("s_waitcnt vmcnt(0)" ::: "memory")

// ---- prep: psp transpose+cvt AND both weight cvts, one kernel ------------
__global__ __launch_bounds__(256) void prep(
    const float* __restrict__ psp, bf16_t* __restrict__ pspT,
    const float4* __restrict__ w1, bf16x4v* __restrict__ o1, int n1,
    const float4* __restrict__ w2, bf16x4v* __restrict__ o2, int n2) {
  __shared__ float tile[64][65];
  const int tid = threadIdx.x;
  const int b = blockIdx.x;
  const int c0 = (b & 63) * 64;   // batch dim
  const int r0 = (b >> 6) * 64;   // in dim
  const int tx = tid & 63;
  const int ty = tid >> 6;
#pragma unroll
  for (int i = 0; i < 16; ++i) {
    const int r = ty + i * 4;
    tile[r][tx] = psp[(size_t)(r0 + r) * 4096 + c0 + tx];
  }
  const int base = b * 768 + tid;
#pragma unroll
  for (int i = 0; i < 3; ++i) {
    const int idx = base + i * 256;
    const float4 v = (idx < n1) ? w1[idx] : w2[idx - n1];
    bf16x4v o;
    o.x = (bf16_t)v.x; o.y = (bf16_t)v.y; o.z = (bf16_t)v.z; o.w = (bf16_t)v.w;
    if (idx < n1) o1[idx] = o;
    else if (idx - n1 < n2) o2[idx - n1] = o;
  }
  __syncthreads();
#pragma unroll
  for (int i = 0; i < 16; ++i) {
    const int r = ty + i * 4;
    pspT[(size_t)(c0 + r) * 1024 + r0 + tx] = (bf16_t)tile[tx][r];
  }
}

// ---- GEMM1: R(bf16) = 0.35*sigmoid(6/7*(A @ Bt^T + bias)) ----------------
// 128x64 tile, 4 waves of 64x32, BK=64, grid (32,32)=1024, dbuf LDS 48 KB
// (3 blocks/CU). Staging: 8-row chunks, LDS slot seg = gseg^(row&7).
__global__ __launch_bounds__(256, 3) void gemm1_nt(
    const bf16_t* __restrict__ A, const bf16_t* __restrict__ Bt,
    const float* __restrict__ bias, bf16_t* __restrict__ C,
    int M, int N, int K) {
  constexpr int BK = 64;
  __shared__ __align__(16) bf16_t sA[2][128 * BK];  // 32 KB
  __shared__ __align__(16) bf16_t sB[2][64 * BK];   // 16 KB

  const int tid = threadIdx.x;
  const int wave = tid >> 6;
  const int lane = tid & 63;
  const int bm = blockIdx.x * 128;
  const int bn = blockIdx.y * 64;
  const int wm = (wave & 1) * 64;
  const int wn = (wave >> 1) * 32;

  f32x4 acc[4][2] = {};

  const int srow8 = lane >> 3;
  const int gseg = (lane & 7) ^ srow8;
  const bf16_t* Ag = A + (size_t)(bm + wave * 32 + srow8) * K + gseg * 8;
  const bf16_t* Bg = Bt + (size_t)(bn + wave * 16 + srow8) * K + gseg * 8;
  const int dstA = wave * 2048;
  const int dstB = wave * 1024;

#define STG1(k0, b)                                                     \
  do {                                                                  \
    _Pragma("unroll") for (int c = 0; c < 4; ++c)                       \
        GLD_TO_LDS16(Ag + (size_t)(c * 8) * K + (k0),                   \
                     &sA[b][dstA + c * 512]);                           \
    _Pragma("unroll") for (int c = 0; c < 2; ++c)                       \
        GLD_TO_LDS16(Bg + (size_t)(c * 8) * K + (k0),                   \
                     &sB[b][dstB + c * 512]);                           \
  } while (0)

  const int fr = lane & 15;
  const int qh = lane >> 4;

  STG1(0, 0);
  DRAIN_VM();
  __syncthreads();
  int p = 0;
  for (int k0 = 0; k0 < K; k0 += BK) {
    if (k0 + BK < K) STG1(k0 + BK, p ^ 1);  // prefetch overlaps compute
#pragma unroll
    for (int ks = 0; ks < 2; ++ks) {
      const int q = ks * 4 + qh;
      bf16x8 av[4], bv[2];
#pragma unroll
      for (int i = 0; i < 4; ++i) {
        const int rr = wm + i * 16 + fr;
        av[i] = *(const bf16x8*)(&sA[p][rr * BK + ((q ^ (rr & 7)) * 8)]);
      }
#pragma unroll
      for (int j = 0; j < 2; ++j) {
        const int rr = wn + j * 16 + fr;
        bv[j] = *(const bf16x8*)(&sB[p][rr * BK + ((q ^ (rr & 7)) * 8)]);
      }
#pragma unroll
      for (int i = 0; i < 4; ++i)
#pragma unroll
        for (int j = 0; j < 2; ++j)
          acc[i][j] = __builtin_amdgcn_mfma_f32_16x16x32_bf16(
              av[i], bv[j], acc[i][j], 0, 0, 0);
    }
    DRAIN_VM();       // every wave's prefetch DMA has landed
    __syncthreads();  // cross-wave publish + protect old buffer reuse
    p ^= 1;
  }
#undef STG1

  const int cm0 = (lane >> 4) * 4;
#pragma unroll
  for (int j = 0; j < 2; ++j) {
    const int gn = bn + wn + j * 16 + fr;
    const float bj = bias[gn];
#pragma unroll
    for (int i = 0; i < 4; ++i) {
#pragma unroll
      for (int r = 0; r < 4; ++r) {
        const int gm = bm + wm + i * 16 + cm0 + r;
        const float z = 0.8571428571428571f * (acc[i][j][r] + bj);
        C[(size_t)gm * N + gn] = (bf16_t)(0.35f / (1.0f + __expf(-z)));
      }
    }
  }
}

// ---- GEMM2: out(fp32) = 0.35*sigmoid(0.75*(R @ Wo^T + b_o) + 0.125*lbl) --
// 32x64 tile, 4 waves of 16x32, BK=64, grid (128,8)=1024, dbuf LDS 24 KB.
__global__ __launch_bounds__(256, 4) void gemm2_nt(
    const bf16_t* __restrict__ A, const bf16_t* __restrict__ Bt,
    const float* __restrict__ bias, const float* __restrict__ lbl,
    float* __restrict__ out, int M, int N, int K) {
  constexpr int BK = 64;
  __shared__ __align__(16) bf16_t sA[2][32 * BK];  // 8 KB
  __shared__ __align__(16) bf16_t sB[2][64 * BK];  // 16 KB

  const int tid = threadIdx.x;
  const int wave = tid >> 6;
  const int lane = tid & 63;
  const int bm = blockIdx.x * 32;
  const int bn = blockIdx.y * 64;
  const int wm = (wave & 1) * 16;
  const int wn = (wave >> 1) * 32;

  f32x4 acc[2] = {};

  const int srow8 = lane >> 3;
  const int gseg = (lane & 7) ^ srow8;
  const bf16_t* Ag = A + (size_t)(bm + wave * 8 + srow8) * K + gseg * 8;
  const bf16_t* Bg = Bt + (size_t)(bn + wave * 16 + srow8) * K + gseg * 8;
  const int dstA = wave * 512;
  const int dstB = wave * 1024;

#define STG2(k0, b)                                                     \
  do {                                                                  \
    GLD_TO_LDS16(Ag + (k0), &sA[b][dstA]);                              \
    _Pragma("unroll") for (int c = 0; c < 2; ++c)                       \
        GLD_TO_LDS16(Bg + (size_t)(c * 8) * K + (k0),                   \
                     &sB[b][dstB + c * 512]);                           \
  } while (0)

  const int fr = lane & 15;
  const int qh = lane >> 4;

  STG2(0, 0);
  DRAIN_VM();
  __syncthreads();
  int p = 0;
  for (int k0 = 0; k0 < K; k0 += BK) {
    if (k0 + BK < K) STG2(k0 + BK, p ^ 1);
#pragma unroll
    for (int ks = 0; ks < 2; ++ks) {
      const int q = ks * 4 + qh;
      const int ra = wm + fr;
      const bf16x8 av =
          *(const bf16x8*)(&sA[p][ra * BK + ((q ^ (ra & 7)) * 8)]);
      bf16x8 bv[2];
#pragma unroll
      for (int j = 0; j < 2; ++j) {
        const int rr = wn + j * 16 + fr;
        bv[j] = *(const bf16x8*)(&sB[p][rr * BK + ((q ^ (rr & 7)) * 8)]);
      }
#pragma unroll
      for (int j = 0; j < 2; ++j)
        acc[j] = __builtin_amdgcn_mfma_f32_16x16x32_bf16(av, bv[j], acc[j],
                                                         0, 0, 0);
    }
    DRAIN_VM();
    __syncthreads();
    p ^= 1;
  }
#undef STG2

  const int cm0 = (lane >> 4) * 4;
#pragma unroll
  for (int j = 0; j < 2; ++j) {
    const int gn = bn + wn + j * 16 + fr;
    const float bj = bias[gn];
#pragma unroll
    for (int r = 0; r < 4; ++r) {
      const int gm = bm + wm + cm0 + r;
      const float z =
          0.75f * (acc[j][r] + bj) + 0.125f * lbl[(size_t)gm * N + gn];
      out[(size_t)gm * N + gn] = 0.35f / (1.0f + __expf(-z));
    }
  }
}

extern "C" void kernel_launch(void* const* d_in, const int* in_sizes, int n_in,
                              void* d_out, int out_size, void* d_ws, size_t ws_size,
                              hipStream_t stream) {
  constexpr int IN = 1024, HID = 2048, OUT = 512, B = 4096;
  const float* psp = (const float*)d_in[0];   // [IN, B]
  const float* lbl = (const float*)d_in[1];   // [B, OUT]
  const float* W_h = (const float*)d_in[2];   // [HID, IN]
  const float* b_h = (const float*)d_in[3];   // [HID]
  const float* W_o = (const float*)d_in[4];   // [OUT, HID]
  const float* b_o = (const float*)d_in[5];   // [OUT]
  float* out = (float*)d_out;                 // [B, OUT] fp32

  bf16_t* Whb = (bf16_t*)d_ws;                 // [HID, IN]  4 MB
  bf16_t* Wob = Whb + (size_t)HID * IN;        // [OUT, HID] 2 MB
  bf16_t* pspT = Wob + (size_t)OUT * HID;      // [B, IN]    8 MB
  bf16_t* Rm = pspT + (size_t)B * IN;          // [B, HID]  16 MB

  prep<<<1024, 256, 0, stream>>>(
      psp, pspT, (const float4*)W_h, (bf16x4v*)Whb, HID * IN / 4,
      (const float4*)W_o, (bf16x4v*)Wob, OUT * HID / 4);
  gemm1_nt<<<dim3(B / 128, HID / 64), 256, 0, stream>>>(
      pspT, Whb, b_h, Rm, B, HID, IN);
  gemm2_nt<<<dim3(B / 32, OUT / 64), 256, 0, stream>>>(
      Rm, Wob, b_o, lbl, out, B, OUT, HID);
}

// Round 13
// 132.243 us; speedup vs baseline: 1.4817x; 1.0691x over previous
//
#include <hip/hip_runtime.h>
#include <hip/hip_bf16.h>

// Net_27358941675610: the 50-step scan collapses to its fixed point:
//   R   = 0.35*sigmoid((6/7)*(psp^T @ W_h^T + b_h))            [4096,2048]
//   out = 0.35*sigmoid(0.75*(R @ W_o^T + b_o) + 0.125*label)   [4096,512]
// Inputs fp32, output fp32. Internal: bf16 MFMA, fp32 acc.
// R13: revert R12 dbuf (drain made it = single-buffer at lower occupancy).
// GEMM1 moves to mfma_32x32x16 with 128x128/4-wave/64x64 wave-tiles:
// 2x FLOP per LDS fragment byte (45.8 vs 68.7 B/kFLOP) -> LDS floor ~10us.
// Staging layout = R8's proven 4-wave 128x128 pattern. GEMM2 = R10 verbatim.

typedef __bf16 bf16_t;
typedef __bf16 bf16x8 __attribute__((ext_vector_type(8)));
typedef __bf16 bf16x4v __attribute__((ext_vector_type(4)));
typedef float f32x4 __attribute__((ext_vector_type(4)));
typedef float f32x16 __attribute__((ext_vector_type(16)));

#define GLD_TO_LDS16(gp, lp)                                            \
  __builtin_amdgcn_global_load_lds(                                     \
      (__attribute__((address_space(1))) void*)(void*)(gp),             \
      (__attribute__((address_space(3))) void*)(lp), 16, 0, 0)

// ---- prep: psp transpose+cvt AND both weight cvts, one kernel ------------
__global__ __launch_bounds__(256) void prep(
    const float* __restrict__ psp, bf16_t* __restrict__ pspT,
    const float4* __restrict__ w1, bf16x4v* __restrict__ o1, int n1,
    const float4* __restrict__ w2, bf16x4v* __restrict__ o2, int n2) {
  __shared__ float tile[64][65];
  const int tid = threadIdx.x;
  const int b = blockIdx.x;
  const int c0 = (b & 63) * 64;   // batch dim
  const int r0 = (b >> 6) * 64;   // in dim
  const int tx = tid & 63;
  const int ty = tid >> 6;
#pragma unroll
  for (int i = 0; i < 16; ++i) {
    const int r = ty + i * 4;
    tile[r][tx] = psp[(size_t)(r0 + r) * 4096 + c0 + tx];
  }
  const int base = b * 768 + tid;
#pragma unroll
  for (int i = 0; i < 3; ++i) {
    const int idx = base + i * 256;
    const float4 v = (idx < n1) ? w1[idx] : w2[idx - n1];
    bf16x4v o;
    o.x = (bf16_t)v.x; o.y = (bf16_t)v.y; o.z = (bf16_t)v.z; o.w = (bf16_t)v.w;
    if (idx < n1) o1[idx] = o;
    else if (idx - n1 < n2) o2[idx - n1] = o;
  }
  __syncthreads();
#pragma unroll
  for (int i = 0; i < 16; ++i) {
    const int r = ty + i * 4;
    pspT[(size_t)(c0 + r) * 1024 + r0 + tx] = (bf16_t)tile[tx][r];
  }
}

// ---- GEMM1: R(bf16) = 0.35*sigmoid(6/7*(A @ Bt^T + bias)) ----------------
// mfma_f32_32x32x16_bf16. 128x128 tile, 4 waves of 64x64 (2x2 of 32x32),
// BK=64, single-buffer LDS 32KB, grid (32,16)=512 -> 2 blocks/CU.
// Staging (R8-proven): wave w stages A+B rows w*32..w*32+31 as 4 chunks of
// 8 rows; LDS slot (row, s) holds global 16B-seg s ^ (row & 7).
// Fragment (32x32x16): A[row=lane&31][k=(lane>>5)*8+j]; C/D col=lane&31,
// row=(reg&3)+8*(reg>>2)+4*(lane>>5)  [m74/m101].
__global__ __launch_bounds__(256, 2) void gemm1_nt(
    const bf16_t* __restrict__ A, const bf16_t* __restrict__ Bt,
    const float* __restrict__ bias, bf16_t* __restrict__ C,
    int M, int N, int K) {
  constexpr int BK = 64;
  __shared__ __align__(16) bf16_t sA[128 * BK];  // 16 KB
  __shared__ __align__(16) bf16_t sB[128 * BK];  // 16 KB

  const int tid = threadIdx.x;
  const int wave = tid >> 6;  // 0..3
  const int lane = tid & 63;
  const int bm = blockIdx.x * 128;
  const int bn = blockIdx.y * 128;
  const int wm = (wave & 1) * 64;
  const int wn = (wave >> 1) * 64;

  f32x16 acc[2][2] = {};

  const int srow8 = lane >> 3;
  const int gseg = (lane & 7) ^ srow8;
  const bf16_t* Ag = A + (size_t)(bm + wave * 32 + srow8) * K + gseg * 8;
  const bf16_t* Bg = Bt + (size_t)(bn + wave * 32 + srow8) * K + gseg * 8;
  const int dst = wave * 2048;  // 4 chunks x 512 elements

  const int col = lane & 31;     // fragment row (A) / col (B/D)
  const int g = lane >> 5;       // k-half 0..1

  for (int k0 = 0; k0 < K; k0 += BK) {
#pragma unroll
    for (int c = 0; c < 4; ++c) {
      GLD_TO_LDS16(Ag + (size_t)(c * 8) * K + k0, sA + dst + c * 512);
      GLD_TO_LDS16(Bg + (size_t)(c * 8) * K + k0, sB + dst + c * 512);
    }
    __syncthreads();  // vmcnt drained at barrier: tiles published

#pragma unroll
    for (int ks = 0; ks < 4; ++ks) {  // four K=16 steps per BK=64
      const int q = ks * 2 + g;       // 16B segment 0..7
      bf16x8 av[2], bv[2];
#pragma unroll
      for (int i = 0; i < 2; ++i) {
        const int rr = wm + i * 32 + col;
        av[i] = *(const bf16x8*)(sA + rr * BK + ((q ^ (rr & 7)) * 8));
      }
#pragma unroll
      for (int j = 0; j < 2; ++j) {
        const int rr = wn + j * 32 + col;
        bv[j] = *(const bf16x8*)(sB + rr * BK + ((q ^ (rr & 7)) * 8));
      }
#pragma unroll
      for (int i = 0; i < 2; ++i)
#pragma unroll
        for (int j = 0; j < 2; ++j)
          acc[i][j] = __builtin_amdgcn_mfma_f32_32x32x16_bf16(
              av[i], bv[j], acc[i][j], 0, 0, 0);
    }
    __syncthreads();  // protects buffer reuse
  }

  // epilogue: col = lane&31, row = (reg&3) + 8*(reg>>2) + 4*(lane>>5)
  const int rbase = 4 * g;
#pragma unroll
  for (int j = 0; j < 2; ++j) {
    const int gn = bn + wn + j * 32 + col;
    const float bj = bias[gn];
#pragma unroll
    for (int i = 0; i < 2; ++i) {
#pragma unroll
      for (int r = 0; r < 16; ++r) {
        const int gm = bm + wm + i * 32 + (r & 3) + 8 * (r >> 2) + rbase;
        const float z = 0.8571428571428571f * (acc[i][j][r] + bj);
        C[(size_t)gm * N + gn] = (bf16_t)(0.35f / (1.0f + __expf(-z)));
      }
    }
  }
}

// ---- GEMM2: out(fp32) = 0.35*sigmoid(0.75*(R @ Wo^T + b_o) + 0.125*lbl) --
// R10 verbatim (proven). 32x64 tile, 4 waves of 16x32, BK=64, grid 1024.
__global__ __launch_bounds__(256, 4) void gemm2_nt(
    const bf16_t* __restrict__ A, const bf16_t* __restrict__ Bt,
    const float* __restrict__ bias, const float* __restrict__ lbl,
    float* __restrict__ out, int M, int N, int K) {
  constexpr int BK = 64;
  __shared__ __align__(16) bf16_t sA[32 * BK];  // 4 KB
  __shared__ __align__(16) bf16_t sB[64 * BK];  // 8 KB

  const int tid = threadIdx.x;
  const int wave = tid >> 6;
  const int lane = tid & 63;
  const int bm = blockIdx.x * 32;
  const int bn = blockIdx.y * 64;
  const int wm = (wave & 1) * 16;
  const int wn = (wave >> 1) * 32;

  f32x4 acc[2] = {};

  const int srow8 = lane >> 3;
  const int gseg = (lane & 7) ^ srow8;
  const bf16_t* Ag = A + (size_t)(bm + wave * 8 + srow8) * K + gseg * 8;
  const bf16_t* Bg = Bt + (size_t)(bn + wave * 16 + srow8) * K + gseg * 8;
  const int dstA = wave * 512;
  const int dstB = wave * 1024;

  const int fr = lane & 15;
  const int qh = lane >> 4;

  for (int k0 = 0; k0 < K; k0 += BK) {
    GLD_TO_LDS16(Ag + k0, sA + dstA);
#pragma unroll
    for (int c = 0; c < 2; ++c)
      GLD_TO_LDS16(Bg + (size_t)(c * 8) * K + k0, sB + dstB + c * 512);
    __syncthreads();

#pragma unroll
    for (int ks = 0; ks < 2; ++ks) {
      const int q = ks * 4 + qh;
      const int ra = wm + fr;
      const bf16x8 av = *(const bf16x8*)(sA + ra * BK + ((q ^ (ra & 7)) * 8));
      bf16x8 bv[2];
#pragma unroll
      for (int j = 0; j < 2; ++j) {
        const int rr = wn + j * 16 + fr;
        bv[j] = *(const bf16x8*)(sB + rr * BK + ((q ^ (rr & 7)) * 8));
      }
#pragma unroll
      for (int j = 0; j < 2; ++j)
        acc[j] = __builtin_amdgcn_mfma_f32_16x16x32_bf16(av, bv[j], acc[j],
                                                         0, 0, 0);
    }
    __syncthreads();
  }

  const int cm0 = (lane >> 4) * 4;
#pragma unroll
  for (int j = 0; j < 2; ++j) {
    const int gn = bn + wn + j * 16 + fr;
    const float bj = bias[gn];
#pragma unroll
    for (int r = 0; r < 4; ++r) {
      const int gm = bm + wm + cm0 + r;
      const float z =
          0.75f * (acc[j][r] + bj) + 0.125f * lbl[(size_t)gm * N + gn];
      out[(size_t)gm * N + gn] = 0.35f / (1.0f + __expf(-z));
    }
  }
}

extern "C" void kernel_launch(void* const* d_in, const int* in_sizes, int n_in,
                              void* d_out, int out_size, void* d_ws, size_t ws_size,
                              hipStream_t stream) {
  constexpr int IN = 1024, HID = 2048, OUT = 512, B = 4096;
  const float* psp = (const float*)d_in[0];   // [IN, B]
  const float* lbl = (const float*)d_in[1];   // [B, OUT]
  const float* W_h = (const float*)d_in[2];   // [HID, IN]
  const float* b_h = (const float*)d_in[3];   // [HID]
  const float* W_o = (const float*)d_in[4];   // [OUT, HID]
  const float* b_o = (const float*)d_in[5];   // [OUT]
  float* out = (float*)d_out;                 // [B, OUT] fp32

  bf16_t* Whb = (bf16_t*)d_ws;                 // [HID, IN]  4 MB
  bf16_t* Wob = Whb + (size_t)HID * IN;        // [OUT, HID] 2 MB
  bf16_t* pspT = Wob + (size_t)OUT * HID;      // [B, IN]    8 MB
  bf16_t* Rm = pspT + (size_t)B * IN;          // [B, HID]  16 MB

  prep<<<1024, 256, 0, stream>>>(
      psp, pspT, (const float4*)W_h, (bf16x4v*)Whb, HID * IN / 4,
      (const float4*)W_o, (bf16x4v*)Wob, OUT * HID / 4);
  gemm1_nt<<<dim3(B / 128, HID / 128), 256, 0, stream>>>(
      pspT, Whb, b_h, Rm, B, HID, IN);
  gemm2_nt<<<dim3(B / 32, OUT / 64), 256, 0, stream>>>(
      Rm, Wob, b_o, lbl, out, B, OUT, HID);
}